// Round 2
// baseline (355.892 us; speedup 1.0000x reference)
//
#include <hip/hip_runtime.h>
#include <math.h>

// CTC greedy decoder: argmax over V, then per-row unique_consecutive + blank-drop + compact.
// B=64, T=2048, V=512 (fp32 probs, int32 lengths, int32 outputs).

#define VDIM 512
#define TDIM 2048

// 16 lanes per (b,t) row; 4 rows per wave; 16 rows per 256-thread block.
// Each lane: 8 independent float4 loads (128 B in flight -> high MLP),
// local argmax over 32 elems (strict > keeps first occurrence; per-lane
// indices ascend), then 4-step butterfly within the 16-lane group with
// (val desc, idx asc) tie-break. Only 8 ds-permute ops per wave (2/row)
// vs 12/row in the 64-lane version.
__global__ __launch_bounds__(256) void argmax_rows(const float* __restrict__ probs,
                                                   int* __restrict__ tokens,
                                                   int nrows) {
    int wave = (blockIdx.x * blockDim.x + threadIdx.x) >> 6;
    int lane = threadIdx.x & 63;
    int g = lane >> 4;          // row within wave's group of 4
    int s = lane & 15;          // sub-lane within the 16-lane row team
    int row = wave * 4 + g;
    if (row >= nrows) return;

    const float4* p = (const float4*)(probs + (size_t)row * VDIM) + s;
    float4 v[8];
    #pragma unroll
    for (int k = 0; k < 8; k++) v[k] = p[k * 16];   // chunk k: elems k*64 + s*4 ..+3

    float bv = -INFINITY; int bi = 0;
    #pragma unroll
    for (int k = 0; k < 8; k++) {
        int base = k * 64 + s * 4;
        if (v[k].x > bv) { bv = v[k].x; bi = base;     }
        if (v[k].y > bv) { bv = v[k].y; bi = base + 1; }
        if (v[k].z > bv) { bv = v[k].z; bi = base + 2; }
        if (v[k].w > bv) { bv = v[k].w; bi = base + 3; }
    }

    // butterfly within the 16-lane group; ties -> lower index (first occurrence)
    #pragma unroll
    for (int off = 8; off > 0; off >>= 1) {
        float ov = __shfl_xor(bv, off, 64);
        int   oi = __shfl_xor(bi, off, 64);
        if (ov > bv || (ov == bv && oi < bi)) { bv = ov; bi = oi; }
    }
    if (s == 0) tokens[row] = bi;
}

// One block (256 threads) per batch row; 8 tokens/thread over T=2048.
// keep = (t < len) && (tok != 0) && (tok != prev); prefix-scan; compact left; zero tail.
// All global READS happen before the first __syncthreads so the kernel is safe
// even if `tokens` aliases `out` (workspace fallback).
__global__ __launch_bounds__(256) void ctc_compact(const int* __restrict__ tokens,
                                                   const int* __restrict__ lengths,
                                                   int* __restrict__ out,
                                                   int* __restrict__ out_lengths) {
    const int b = blockIdx.x;
    const int tid = threadIdx.x;
    const int t0 = tid * 8;

    const int* row = tokens + (size_t)b * TDIM;

    // load 8 tokens (2x int4) + predecessor
    int4 lo = ((const int4*)(row + t0))[0];
    int4 hi = ((const int4*)(row + t0))[1];
    int tok[8] = { lo.x, lo.y, lo.z, lo.w, hi.x, hi.y, hi.z, hi.w };
    int prev = (t0 == 0) ? -1 : row[t0 - 1];

    int len = lengths[b];
    if (len < 0) len = 0;
    if (len > TDIM) len = TDIM;

    // thread-local keep flags + exclusive positions
    int pos[8];
    unsigned kb = 0;
    int c = 0;
    #pragma unroll
    for (int j = 0; j < 8; j++) {
        int t = t0 + j;
        int tk = tok[j];
        bool keep = (t < len) & (tk != 0) & (tk != prev);
        pos[j] = c;
        if (keep) { kb |= (1u << j); c++; }
        prev = tk;
    }

    // block exclusive scan of c: wave shuffle scan + 4-wave LDS combine
    int lane = tid & 63;
    int wid = tid >> 6;
    int incl = c;
    #pragma unroll
    for (int off = 1; off < 64; off <<= 1) {
        int n = __shfl_up(incl, off, 64);
        if (lane >= off) incl += n;
    }
    __shared__ int wsum[4];
    if (lane == 63) wsum[wid] = incl;
    __syncthreads();
    int wbase = 0;
    #pragma unroll
    for (int w = 0; w < 4; w++) {
        int sv = wsum[w];
        if (w < wid) wbase += sv;
    }
    int excl = wbase + incl - c;
    int total = wsum[0] + wsum[1] + wsum[2] + wsum[3];

    // scatter kept tokens to [0, total)
    int* orow = out + (size_t)b * TDIM;
    #pragma unroll
    for (int j = 0; j < 8; j++) {
        if ((kb >> j) & 1u) orow[excl + pos[j]] = tok[j];
    }
    // zero-fill [total, T)  (d_out is poisoned before every run)
    for (int t = total + tid; t < TDIM; t += 256) orow[t] = 0;

    if (tid == 0) out_lengths[b] = total;
}

extern "C" void kernel_launch(void* const* d_in, const int* in_sizes, int n_in,
                              void* d_out, int out_size, void* d_ws, size_t ws_size,
                              hipStream_t stream) {
    const float* probs = (const float*)d_in[0];
    const int* lengths = (const int*)d_in[1];
    int* out = (int*)d_out;

    const int B = in_sizes[1];              // 64
    const int nrows = in_sizes[0] / VDIM;   // B*T = 131072

    // tokens scratch: B*T int32 = 512 KB; fall back to in-place in d_out if ws too small
    int* tokens = (ws_size >= (size_t)nrows * sizeof(int)) ? (int*)d_ws : out;

    // 16 rows per 256-thread block (4 rows/wave, 16 lanes/row)
    argmax_rows<<<(nrows + 15) / 16, 256, 0, stream>>>(probs, tokens, nrows);
    ctc_compact<<<B, 256, 0, stream>>>(tokens, lengths, out, out + nrows);
}